// Round 14
// baseline (72.334 us; speedup 1.0000x reference)
//
#include <hip/hip_runtime.h>

#define TSIZE 512
#define NT 512
#define EPSV 1e-9f

// SINGLE fused kernel, full-row blocks. Grid = 512 (block = row i), 512 thr =
// 8 waves = 4 strips of 128 px x 2 tri-halves. Lane = 2 pixels (j, j+64):
// each survivor record fetch serves 2 pixels -> ~40% fewer LDS broadcasts.
//  1. stage raw tris (18 KB) into LDS.
//  2. thread t: record for tri t (R4 layout) -> LDS; AABB ints; ONE row-slice
//     y-interval (conservative); 4 per-128px-strip window tests -> 4 __ballot
//     -> 32 survivor words in LDS. zmin reduced in-block.
//  3. wave w: strip k=w>>1, tri-half h=w&1; pops words (uniform SALU ctz),
//     evals 2 px/lane from LDS broadcasts (px-side products computed once and
//     reused -> identical rounded values), tracks (zb,tw) x2.
//  4. per-strip 2-way lex-merge (painter == lex-argmax(pz,t), R7-validated),
//     one exact winner interpolation, coalesced full-row store.
// No workspace. Sign-determining chains bit-exact vs numpy (__f*_rn, same
// order, same single-rounded diffs as R4..R13); cull math conservative-only.

__device__ __forceinline__ float rcp_fast(float x) {
  float r;
  asm("v_rcp_f32 %0, %1" : "=v"(r) : "v"(x));
  return r;
}

__global__ __launch_bounds__(512) void render_fused(const float* __restrict__ tris,
                                                    float4* __restrict__ out) {
  __shared__ float4 lrec[NT * 4];             // 32 KB; first 18 KB doubles as raw stage
  __shared__ unsigned lbY[NT];                // 2 KB ym|yM<<16
  __shared__ float2 smrg[1024];               // 8 KB: [strip][half][128 px]
  __shared__ unsigned long long swords[32];   // 4 strips x 8 tri-words
  __shared__ float sred[8];

  const int tid = threadIdx.x;      // 0..511
  const int i = blockIdx.x;         // row 0..511 (block-uniform)
  const float delta = 2.0f / 511.0f;

  // ---- 1. stage raw tris ----
  {
    const float4* g4 = (const float4*)tris;
    float4* rw4 = lrec;
    rw4[tid] = g4[tid];
    rw4[tid + 512] = g4[tid + 512];
    if (tid < 128) rw4[tid + 1024] = g4[tid + 1024];
  }
  __syncthreads();

  // ---- 2. per-tri record + row-slice cull + 4 strip ballots ----
  const float* rawf = (const float*)lrec;
  const float* tp = rawf + tid * 9;
  float v0x = tp[0], v0y = tp[1], v0z = tp[2];
  float v1x = tp[3], v1y = tp[4], v1z = tp[5];
  float v2x = tp[6], v2y = tp[7], v2z = tp[8];
  __syncthreads();   // raw values now in registers -> safe to overwrite lrec

  float w = __fsub_rn(__fmul_rn(__fsub_rn(v1x, v0x), __fsub_rn(v2y, v0y)),
                      __fmul_rn(__fsub_rn(v1y, v0y), __fsub_rn(v2x, v0x)));
  bool valid = (w >= EPSV);
  float ws = valid ? w : 1.0f;
  float r2  = __fsub_rn(v0y, v1y), r3  = __fsub_rn(v0x, v1x);
  float r6  = __fsub_rn(v1y, v2y), r7  = __fsub_rn(v1x, v2x);
  float r10 = __fsub_rn(v2y, v0y), r11 = __fsub_rn(v2x, v0x);

  int xmn = 0, xmx = 0, ymn = 0, ymx = 0;
  if (valid) {
    float bxn = fminf(v0x, fminf(v1x, v2x));
    float byn = fminf(v0y, fminf(v1y, v2y));
    float bxx = fmaxf(v0x, fmaxf(v1x, v2x));
    float byx = fmaxf(v0y, fmaxf(v1y, v2y));
    xmn = (int)floorf(__fmul_rn(__fadd_rn(fminf(fmaxf(bxn, -1.0f), 1.0f), 1.0f), 256.0f));
    ymn = (int)floorf(__fmul_rn(__fadd_rn(fminf(fmaxf(byn, -1.0f), 1.0f), 1.0f), 256.0f));
    xmx = (int)floorf(__fmul_rn(__fadd_rn(fminf(fmaxf(bxx, -1.0f), 1.0f), 1.0f), 256.0f));
    ymx = (int)floorf(__fmul_rn(__fadd_rn(fminf(fmaxf(byx, -1.0f), 1.0f), 1.0f), 256.0f));
  }

  const bool xpass = ((unsigned)i >= (unsigned)xmn) & ((unsigned)i < (unsigned)xmx);
  float ylo = -1e30f, yhi = 1e30f;
  if (xpass) {
    const float px_s = -1.0f + (float)i * delta;
    {
      float S = -r3, c = (v1y * r3 - v1x * r2) + r2 * px_s;
      if (S > 1e-20f)       { float cd = -c * rcp_fast(S); ylo = fmaxf(ylo, cd - (0.005f + 4e-6f * fabsf(cd))); }
      else if (S < -1e-20f) { float cd = -c * rcp_fast(S); yhi = fminf(yhi, cd + (0.005f + 4e-6f * fabsf(cd))); }
    }
    {
      float S = -r7, c = (v2y * r7 - v2x * r6) + r6 * px_s;
      if (S > 1e-20f)       { float cd = -c * rcp_fast(S); ylo = fmaxf(ylo, cd - (0.005f + 4e-6f * fabsf(cd))); }
      else if (S < -1e-20f) { float cd = -c * rcp_fast(S); yhi = fminf(yhi, cd + (0.005f + 4e-6f * fabsf(cd))); }
    }
    {
      float S = -r11, c = (v0y * r11 - v0x * r10) + r10 * px_s;
      if (S > 1e-20f)       { float cd = -c * rcp_fast(S); ylo = fmaxf(ylo, cd - (0.005f + 4e-6f * fabsf(cd))); }
      else if (S < -1e-20f) { float cd = -c * rcp_fast(S); yhi = fminf(yhi, cd + (0.005f + 4e-6f * fabsf(cd))); }
    }
  }

  // 4 per-strip (128 px) ballots
#pragma unroll
  for (int k = 0; k < 4; ++k) {
    const unsigned jw0 = (unsigned)(k << 7);
    const float pyL = -1.0f + (float)jw0 * delta;
    const float pyR = -1.0f + (float)(jw0 + 127u) * delta;
    bool pk = xpass & ((unsigned)ymn < jw0 + 128u) & ((unsigned)ymx > jw0) &
              (ylo <= pyR) & (yhi >= pyL);
    unsigned long long wd = __ballot(pk ? 1 : 0);
    if ((tid & 63) == 0) swords[k * 8 + (tid >> 6)] = wd;
  }

  // records + ybnd + zmin
  lrec[tid * 4 + 0] = make_float4(v1x, v1y, r2, r3);
  lrec[tid * 4 + 1] = make_float4(v2x, v2y, r6, r7);
  lrec[tid * 4 + 2] = make_float4(v0x, v0y, r10, r11);
  lrec[tid * 4 + 3] = make_float4(__fdiv_rn(1.0f, ws), v2z,
                                  __fsub_rn(v0z, v2z), __fsub_rn(v1z, v2z));
  lbY[tid] = (unsigned)ymn | ((unsigned)ymx << 16);

  float zp = fminf(v0z, fminf(v1z, v2z));
  for (int off = 32; off > 0; off >>= 1) zp = fminf(zp, __shfl_down(zp, off, 64));
  if ((tid & 63) == 0) sred[tid >> 6] = zp;
  __syncthreads();
  float zm0 = sred[0];
#pragma unroll
  for (int kk = 1; kk < 8; ++kk) zm0 = fminf(zm0, sred[kk]);

  // ---- 3. eval: wave w = (strip k=w>>1, tri-half h=w&1); lane = 2 pixels ----
  const int wv = tid >> 6;
  const int lane = tid & 63;
  const int k = wv >> 1;
  const int h = wv & 1;
  const unsigned ju0 = (unsigned)(k << 7) + (unsigned)lane;
  const unsigned ju1 = ju0 + 64u;
  const float px = __fadd_rn(-1.0f, __fmul_rn((float)i, delta));
  const float py0 = __fadd_rn(-1.0f, __fmul_rn((float)ju0, delta));
  const float py1 = __fadd_rn(-1.0f, __fmul_rn((float)ju1, delta));

  float zb0 = zm0, zb1 = zm0;
  int tw0 = -1, tw1 = -1;
#pragma unroll 1
  for (int q = 0; q < 4; ++q) {
    unsigned long long m = swords[k * 8 + h * 4 + q];
    const int tb = (h * 4 + q) << 6;
    while (m) {
      const int t = tb + __builtin_ctzll(m);
      m &= m - 1;
      float4 c0 = lrec[t * 4 + 0];
      float4 c1 = lrec[t * 4 + 1];
      float4 c2 = lrec[t * 4 + 2];
      float4 c3 = lrec[t * 4 + 3];
      unsigned yb = lbY[t];
      const unsigned ym = yb & 0xFFFFu, yM = yb >> 16;
      // px-side products computed once; identical rounded values reused.
      float eA = __fmul_rn(__fsub_rn(px, c0.x), c0.z);
      float eB = __fmul_rn(__fsub_rn(px, c1.x), c1.z);
      float eC = __fmul_rn(__fsub_rn(px, c2.x), c2.z);
      // pixel 0
      {
        float pAB = __fsub_rn(eA, __fmul_rn(__fsub_rn(py0, c0.y), c0.w));
        float pCB = __fsub_rn(eB, __fmul_rn(__fsub_rn(py0, c1.y), c1.w));
        float pCA = __fsub_rn(eC, __fmul_rn(__fsub_rn(py0, c2.y), c2.w));
        bool ins = (pAB > 0.0f) & (pCB > 0.0f) & (pCA > 0.0f) &
                   (ju0 >= ym) & (ju0 < yM);
        float w1 = __fmul_rn(pCB, c3.x);
        float w2 = __fmul_rn(pCA, c3.x);
        float pz = __fmaf_rn(w1, c3.z, __fmaf_rn(w2, c3.w, c3.y));
        bool mk = ins & (pz >= zb0);
        zb0 = mk ? pz : zb0;
        tw0 = mk ? t : tw0;
      }
      // pixel 1
      {
        float pAB = __fsub_rn(eA, __fmul_rn(__fsub_rn(py1, c0.y), c0.w));
        float pCB = __fsub_rn(eB, __fmul_rn(__fsub_rn(py1, c1.y), c1.w));
        float pCA = __fsub_rn(eC, __fmul_rn(__fsub_rn(py1, c2.y), c2.w));
        bool ins = (pAB > 0.0f) & (pCB > 0.0f) & (pCA > 0.0f) &
                   (ju1 >= ym) & (ju1 < yM);
        float w1 = __fmul_rn(pCB, c3.x);
        float w2 = __fmul_rn(pCA, c3.x);
        float pz = __fmaf_rn(w1, c3.z, __fmaf_rn(w2, c3.w, c3.y));
        bool mk = ins & (pz >= zb1);
        zb1 = mk ? pz : zb1;
        tw1 = mk ? t : tw1;
      }
    }
  }
  smrg[k * 256 + h * 128 + lane] = make_float2(zb0, __int_as_float(tw0));
  smrg[k * 256 + h * 128 + lane + 64] = make_float2(zb1, __int_as_float(tw1));
  __syncthreads();

  // ---- 4. per-strip 2-way lex-merge + winner interp (all 512 threads) ----
  {
    const int kp = tid >> 7, lp = tid & 127;
    float2 a = smrg[kp * 256 + lp];          // tri-half 0 (ids 0..255)
    float2 b = smrg[kp * 256 + 128 + lp];    // tri-half 1 (ids 256..511)
    int t0 = __float_as_int(a.y), t1 = __float_as_int(b.y);
    bool win1 = (b.x > a.x) | ((b.x == a.x) & (t1 > t0));
    int twf = win1 ? t1 : t0;
    float zf = win1 ? b.x : a.x;

    const unsigned ju2 = (unsigned)tid;
    const float py2 = __fadd_rn(-1.0f, __fmul_rn((float)ju2, delta));

    float4 res = make_float4(0.0f, 0.0f, 0.0f, 0.0f);
    if (twf >= 0) {
      float4 f1 = lrec[twf * 4 + 1];   // v2x v2y r6 r7
      float4 f2 = lrec[twf * 4 + 2];   // v0x v0y r10 r11
      float4 f3 = lrec[twf * 4 + 3];   // rw v2z d0z d1z
      float pCB = __fsub_rn(__fmul_rn(__fsub_rn(px, f1.x), f1.z),
                            __fmul_rn(__fsub_rn(py2, f1.y), f1.w));
      float pCA = __fsub_rn(__fmul_rn(__fsub_rn(px, f2.x), f2.z),
                            __fmul_rn(__fsub_rn(py2, f2.y), f2.w));
      float w1 = __fmul_rn(pCB, f3.x);
      float w2 = __fmul_rn(pCA, f3.x);
      float rx = __fmaf_rn(w1, -f2.w, __fmaf_rn(w2, f1.w, f1.x));
      float ry = __fmaf_rn(w1, -f2.z, __fmaf_rn(w2, f1.z, f1.y));
      res = make_float4(rx, ry, zf, 1.0f);
    }
    out[((unsigned)i << 9) | ju2] = res;
  }
}

extern "C" void kernel_launch(void* const* d_in, const int* in_sizes, int n_in,
                              void* d_out, int out_size, void* d_ws, size_t ws_size,
                              hipStream_t stream) {
  const float* tris = (const float*)d_in[0];
  float4* out = (float4*)d_out;
  hipLaunchKernelGGL(render_fused, dim3(512), dim3(512), 0, stream, tris, out);
}